// Round 6
// baseline (60.913 us; speedup 1.0000x reference)
//
#include <hip/hip_runtime.h>

// ChamferDistance  B=16, N=M=4096, D=3, fp32 in/out (scalar out).
// MFMA formulation: d(a,b) = sum_k A[k]*B[k] over 13 bf16 hi/lo slots (K=16).
#define BQ     16
#define NPTS   4096
#define TOTAL  (BQ * NPTS)          // 65536 points per side
#define NTILES (TOTAL / 32)         // 2048 fragment tiles per side
#define PANEL_U4   ((size_t)NTILES * 64)          // uint4 elements per side panel
#define PANELS_BYTES ((size_t)2 * PANEL_U4 * 16)  // 4 MiB both sides
#define NBLK_DIR 256                // 16 batches * 16 rowblocks
#define WS_NEED  (PANELS_BYTES + (size_t)2 * NBLK_DIR * 4)

typedef __attribute__((ext_vector_type(8)))  short short8;
typedef __attribute__((ext_vector_type(16))) float f32x16;

__device__ __forceinline__ unsigned short f2bf(float x) {
    union { float f; unsigned u; } v; v.f = x;
    unsigned r = v.u + 0x7FFFu + ((v.u >> 16) & 1u);    // RNE
    return (unsigned short)(r >> 16);
}
__device__ __forceinline__ float bf2f(unsigned short h) {
    union { float f; unsigned u; } v; v.u = ((unsigned)h) << 16; return v.f;
}

// B-role slots, k = 8*g + j (A and B use the SAME k-map; sum is perm-invariant):
//  k0-2: -2bH(xyz)  k3-5: -2bL(xyz)  k6-8: -2bH(xyz)  k9,10: 1,1
//  k11,12: b2H,b2L  k13-15: 0
__device__ __forceinline__ uint4 make_bslots(const float* __restrict__ pts,
                                             int tile, int lane) {
    const int pidx = lane & 31, g = lane >> 5;
    const float* pp = pts + (size_t)(tile * 32 + pidx) * 3;
    const float x = pp[0], y = pp[1], z = pp[2];
    const unsigned short xh = f2bf(x), yh = f2bf(y), zh = f2bf(z);
    const unsigned short xl = f2bf(x - bf2f(xh)), yl = f2bf(y - bf2f(yh)),
                         zl = f2bf(z - bf2f(zh));
    const unsigned short m2xh = f2bf(-2.0f * bf2f(xh)), m2yh = f2bf(-2.0f * bf2f(yh)),
                         m2zh = f2bf(-2.0f * bf2f(zh));
    const unsigned short m2xl = f2bf(-2.0f * bf2f(xl)), m2yl = f2bf(-2.0f * bf2f(yl)),
                         m2zl = f2bf(-2.0f * bf2f(zl));
    const float s2 = fmaf(x, x, fmaf(y, y, z * z));
    const unsigned short s2h = f2bf(s2);
    const unsigned short s2l = f2bf(s2 - bf2f(s2h));
    const unsigned short ONE = 0x3F80;
    unsigned short s[8];
    if (g == 0) { s[0]=m2xh; s[1]=m2yh; s[2]=m2zh; s[3]=m2xl; s[4]=m2yl; s[5]=m2zl; s[6]=m2xh; s[7]=m2yh; }
    else        { s[0]=m2zh; s[1]=ONE;  s[2]=ONE;  s[3]=s2h;  s[4]=s2l;  s[5]=0;    s[6]=0;    s[7]=0;   }
    uint4 o;
    o.x = (unsigned)s[0] | ((unsigned)s[1] << 16);
    o.y = (unsigned)s[2] | ((unsigned)s[3] << 16);
    o.z = (unsigned)s[4] | ((unsigned)s[5] << 16);
    o.w = (unsigned)s[6] | ((unsigned)s[7] << 16);
    return o;
}

// A-role slots paired with B above: k0-2 aH, k3-5 aH, k6-8 aL, k9 a2H,
// k10 a2L, k11,12: 1,1, k13-15: 0.
__device__ __forceinline__ short8 make_aslots(const float* __restrict__ pts,
                                              int point, int g) {
    const float* pp = pts + (size_t)point * 3;
    const float x = pp[0], y = pp[1], z = pp[2];
    const unsigned short xh = f2bf(x), yh = f2bf(y), zh = f2bf(z);
    const unsigned short xl = f2bf(x - bf2f(xh)), yl = f2bf(y - bf2f(yh)),
                         zl = f2bf(z - bf2f(zh));
    const float s2 = fmaf(x, x, fmaf(y, y, z * z));
    const unsigned short s2h = f2bf(s2);
    const unsigned short s2l = f2bf(s2 - bf2f(s2h));
    const unsigned short ONE = 0x3F80;
    unsigned short s[8];
    if (g == 0) { s[0]=xh; s[1]=yh; s[2]=zh; s[3]=xh; s[4]=yh; s[5]=zh; s[6]=xl; s[7]=yl; }
    else        { s[0]=zl; s[1]=s2h; s[2]=s2l; s[3]=ONE; s[4]=ONE; s[5]=0; s[6]=0; s[7]=0; }
    union { unsigned u[4]; short8 v; } o;
    o.u[0] = (unsigned)s[0] | ((unsigned)s[1] << 16);
    o.u[1] = (unsigned)s[2] | ((unsigned)s[3] << 16);
    o.u[2] = (unsigned)s[4] | ((unsigned)s[5] << 16);
    o.u[3] = (unsigned)s[6] | ((unsigned)s[7] << 16);
    return o.v;
}

// Build both fragment panels: panels[0]=p1 fragments, panels[1]=p2 fragments.
__global__ __launch_bounds__(256) void cd_prep(const float* __restrict__ p1,
                                               const float* __restrict__ p2,
                                               uint4* __restrict__ panels) {
    const int tid = blockIdx.x * 256 + threadIdx.x;   // [0, 2*TOTAL)
    const int side = (tid >= 2 * TOTAL / 2) ? 1 : 0;  // tid >= 65536*... (2*TOTAL==131072)
    const int loc  = tid - side * (TOTAL);            // careful: TOTAL points -> TOTAL*2 frag-slots? no:
    // each side has NTILES*64 = 131072 (tile,lane) slots?? NTILES*64 = 2048*64 = 131072.
    // 2 sides * 131072 slots = 262144 -> need tid in [0, 262144). Grid = 1024 blocks.
    (void)loc;
    const int s2   = tid >> 17;                       // 0 or 1 (131072 slots per side)
    const int l    = tid & 131071;
    const int tile = l >> 6, lane = l & 63;
    const float* pts = s2 ? p2 : p1;
    panels[((size_t)s2 << 17) + l] = make_bslots(pts, tile, lane);
    (void)side;
}

// Main: 1 wave = 128 rows (4 row-subtiles), block = 128 threads (2 waves, 256 rows).
// Each block sweeps all 128 col-tiles of its batch -> exact row-mins, no atomics.
// grid = (16 batches * 16 rowblocks, 2 dirs).
__global__ __launch_bounds__(128) void cd_mfma(
        const float* __restrict__ p1, const float* __restrict__ p2,
        const uint4* __restrict__ panels, float* __restrict__ partial) {
    const int dir  = blockIdx.y;
    const float* __restrict__ A = dir ? p2 : p1;
    const uint4* __restrict__ panel = panels + ((size_t)(dir ? 0 : 1) << 17);

    const int b    = blockIdx.x >> 4;                 // batch
    const int rb   = blockIdx.x & 15;                 // rowblock (256 rows)
    const int wave = threadIdx.x >> 6;
    const int lane = threadIdx.x & 63;
    const int pidx = lane & 31, g = lane >> 5;

    const int rowbase = b * NPTS + rb * 256 + wave * 128;

    const short8 a0 = make_aslots(A, rowbase       + pidx, g);
    const short8 a1 = make_aslots(A, rowbase + 32  + pidx, g);
    const short8 a2 = make_aslots(A, rowbase + 64  + pidx, g);
    const short8 a3 = make_aslots(A, rowbase + 96  + pidx, g);

    f32x16 zero, r0, r1, r2, r3;
#pragma unroll
    for (int e = 0; e < 16; ++e) {
        zero[e] = 0.0f; r0[e] = 3.0e38f; r1[e] = 3.0e38f;
        r2[e] = 3.0e38f; r3[e] = 3.0e38f;
    }

    const uint4* __restrict__ fp = panel + ((size_t)b * 128 * 64) + lane;

    auto compute = [&](uint4 fa, uint4 fb) {
        const short8 b0 = *reinterpret_cast<const short8*>(&fa);
        const short8 b1 = *reinterpret_cast<const short8*>(&fb);
        f32x16 d0, d1;
        d0 = __builtin_amdgcn_mfma_f32_32x32x16_bf16(a0, b0, zero, 0, 0, 0);
        d1 = __builtin_amdgcn_mfma_f32_32x32x16_bf16(a0, b1, zero, 0, 0, 0);
#pragma unroll
        for (int e = 0; e < 16; ++e) {
            float t; asm("v_min3_f32 %0, %1, %2, %3" : "=v"(t)
                         : "v"(r0[e]), "v"(d0[e]), "v"(d1[e])); r0[e] = t;
        }
        d0 = __builtin_amdgcn_mfma_f32_32x32x16_bf16(a1, b0, zero, 0, 0, 0);
        d1 = __builtin_amdgcn_mfma_f32_32x32x16_bf16(a1, b1, zero, 0, 0, 0);
#pragma unroll
        for (int e = 0; e < 16; ++e) {
            float t; asm("v_min3_f32 %0, %1, %2, %3" : "=v"(t)
                         : "v"(r1[e]), "v"(d0[e]), "v"(d1[e])); r1[e] = t;
        }
        d0 = __builtin_amdgcn_mfma_f32_32x32x16_bf16(a2, b0, zero, 0, 0, 0);
        d1 = __builtin_amdgcn_mfma_f32_32x32x16_bf16(a2, b1, zero, 0, 0, 0);
#pragma unroll
        for (int e = 0; e < 16; ++e) {
            float t; asm("v_min3_f32 %0, %1, %2, %3" : "=v"(t)
                         : "v"(r2[e]), "v"(d0[e]), "v"(d1[e])); r2[e] = t;
        }
        d0 = __builtin_amdgcn_mfma_f32_32x32x16_bf16(a3, b0, zero, 0, 0, 0);
        d1 = __builtin_amdgcn_mfma_f32_32x32x16_bf16(a3, b1, zero, 0, 0, 0);
#pragma unroll
        for (int e = 0; e < 16; ++e) {
            float t; asm("v_min3_f32 %0, %1, %2, %3" : "=v"(t)
                         : "v"(r3[e]), "v"(d0[e]), "v"(d1[e])); r3[e] = t;
        }
    };

    // Two pair-buffers in flight, prefetch 2 pairs ahead (~400 cyc cover).
    uint4 c0 = fp[0 * 64],   c1 = fp[1 * 64];
    uint4 n0 = fp[2 * 64],   n1 = fp[3 * 64];
#pragma unroll 1
    for (int t = 0; t < 128; t += 4) {
        const int ta = (t + 4 > 124) ? 124 : (t + 4);
        uint4 m0 = fp[(size_t)ta * 64], m1 = fp[(size_t)ta * 64 + 64];
        compute(c0, c1);
        const int tb = (t + 6 > 124) ? 124 : (t + 6);
        uint4 q0 = fp[(size_t)tb * 64], q1 = fp[(size_t)tb * 64 + 64];
        compute(n0, n1);
        c0 = m0; c1 = m1; n0 = q0; n1 = q1;
    }

    // Column shuffle-reduce (lanes 0-31 / 32-63 hold distinct rows), then sum
    // every row-min this lane-pair owns; fixed-order block combine.
    float acc = 0.0f;
#pragma unroll
    for (int e = 0; e < 16; ++e) {
        float v0 = r0[e], v1 = r1[e], v2 = r2[e], v3 = r3[e];
#pragma unroll
        for (int m = 1; m <= 16; m <<= 1) {
            v0 = fminf(v0, __shfl_xor(v0, m));
            v1 = fminf(v1, __shfl_xor(v1, m));
            v2 = fminf(v2, __shfl_xor(v2, m));
            v3 = fminf(v3, __shfl_xor(v3, m));
        }
        acc += fmaxf(v0, 0.0f) + fmaxf(v1, 0.0f) + fmaxf(v2, 0.0f) + fmaxf(v3, 0.0f);
    }

    __shared__ float sacc[4];
    if (pidx == 0) sacc[wave * 2 + g] = acc;
    __syncthreads();
    if (threadIdx.x == 0)
        partial[dir * NBLK_DIR + blockIdx.x] =
            ((sacc[0] + sacc[1]) + (sacc[2] + sacc[3]));
}

__global__ __launch_bounds__(512) void cd_final(const float* __restrict__ partial,
                                                float* __restrict__ out) {
    __shared__ float sred[512];
    sred[threadIdx.x] = partial[threadIdx.x];
    __syncthreads();
    for (int st = 256; st > 0; st >>= 1) {
        if (threadIdx.x < st) sred[threadIdx.x] += sred[threadIdx.x + st];
        __syncthreads();
    }
    if (threadIdx.x == 0) out[0] = sred[0] * (1.0f / (float)BQ);
}

// ---------------- fallback (ws too small): R2 LDS-scalar path ----------------
__global__ __launch_bounds__(256) void cd_init_ws(unsigned int* __restrict__ ws) {
    ws[blockIdx.x * 256 + threadIdx.x] = 0x7F800000u;
}
#define F_APT 8
__global__ __launch_bounds__(256) void cd_min_lds(
        const float* __restrict__ p1, const float* __restrict__ p2,
        unsigned int* __restrict__ wsmin) {
    const int dir = blockIdx.y;
    const float* __restrict__ Aset = dir ? p2 : p1;
    const float* __restrict__ Bset = dir ? p1 : p2;
    unsigned int* __restrict__ outmin = wsmin + dir * TOTAL;
    const int atile = blockIdx.x / 16;
    const int mtile = blockIdx.x % 16;
    const int a0 = atile * 2048;
    const int m0 = (a0 / NPTS) * NPTS + mtile * 256;
    __shared__ float4 sbf[256];
    {
        const float* bp = Bset + (size_t)(m0 + threadIdx.x) * 3;
        float bx = bp[0], by = bp[1], bz = bp[2];
        sbf[threadIdx.x] = make_float4(-2.0f*bx, -2.0f*by, -2.0f*bz,
                                       fmaf(bx,bx,fmaf(by,by,bz*bz)));
    }
    __syncthreads();
    float ax[F_APT], ay[F_APT], az[F_APT], q2[F_APT], mn[F_APT];
#pragma unroll
    for (int k = 0; k < F_APT; ++k) {
        const int ai = a0 + k*256 + threadIdx.x;
        const float* ap = Aset + (size_t)ai * 3;
        ax[k]=ap[0]; ay[k]=ap[1]; az[k]=ap[2];
        q2[k]=fmaf(ax[k],ax[k],fmaf(ay[k],ay[k],az[k]*az[k]));
        mn[k]=3.0e38f;
    }
#pragma unroll 2
    for (int j = 0; j < 256; j += 2) {
        const float4 b0 = sbf[j], b1 = sbf[j+1];
#pragma unroll
        for (int k = 0; k < F_APT; ++k) {
            float d0 = fmaf(az[k],b0.z,b0.w); d0=fmaf(ay[k],b0.y,d0); d0=fmaf(ax[k],b0.x,d0);
            float d1 = fmaf(az[k],b1.z,b1.w); d1=fmaf(ay[k],b1.y,d1); d1=fmaf(ax[k],b1.x,d1);
            asm("v_min3_f32 %0, %1, %2, %3" : "=v"(mn[k]) : "v"(mn[k]), "v"(d0), "v"(d1));
        }
    }
#pragma unroll
    for (int k = 0; k < F_APT; ++k) {
        const int ai = a0 + k*256 + threadIdx.x;
        atomicMin(&outmin[ai], __float_as_uint(fmaxf(q2[k]+mn[k], 0.0f)));
    }
}
__global__ __launch_bounds__(1024) void cd_reduce_single(const float* __restrict__ wsmin,
                                                         float* __restrict__ out) {
    __shared__ float sred[1024];
    const float4* __restrict__ v = (const float4*)wsmin;
    float s = 0.0f;
    for (int i = threadIdx.x; i < (2*TOTAL)/4; i += 1024) {
        float4 x = v[i]; s += (x.x + x.y) + (x.z + x.w);
    }
    sred[threadIdx.x] = s;
    __syncthreads();
    for (int st = 512; st > 0; st >>= 1) {
        if (threadIdx.x < st) sred[threadIdx.x] += sred[threadIdx.x + st];
        __syncthreads();
    }
    if (threadIdx.x == 0) out[0] = sred[0] * (1.0f / (float)BQ);
}

extern "C" void kernel_launch(void* const* d_in, const int* in_sizes, int n_in,
                              void* d_out, int out_size, void* d_ws, size_t ws_size,
                              hipStream_t stream) {
    const float* p1 = (const float*)d_in[0];
    const float* p2 = (const float*)d_in[1];
    float* out = (float*)d_out;

    if (ws_size >= WS_NEED) {
        uint4* panels = (uint4*)d_ws;
        float* partial = (float*)((char*)d_ws + PANELS_BYTES);
        cd_prep<<<1024, 256, 0, stream>>>(p1, p2, panels);   // 262144 slots
        dim3 grid(NBLK_DIR, 2, 1);
        cd_mfma<<<grid, 128, 0, stream>>>(p1, p2, panels, partial);
        cd_final<<<1, 512, 0, stream>>>(partial, out);
    } else {
        unsigned* wsmin = (unsigned*)d_ws;                   // 512 KiB
        cd_init_ws<<<(2 * TOTAL) / 256, 256, 0, stream>>>(wsmin);
        dim3 grid(512, 2, 1);
        cd_min_lds<<<grid, 256, 0, stream>>>(p1, p2, wsmin);
        cd_reduce_single<<<1, 1024, 0, stream>>>((const float*)wsmin, out);
    }
}

// Round 7
// 54.272 us; speedup vs baseline: 1.1224x; 1.1224x over previous
//
#include <hip/hip_runtime.h>

// ChamferDistance  B=16, N=M=4096, D=3, fp32 in/out (scalar out).
// MFMA formulation: d(a,b) = sum_k A[k]*B[k] over 13 bf16 hi/lo slots (K=16).
#define BQ     16
#define NPTS   4096
#define TOTAL  (BQ * NPTS)          // 65536 points per side
#define NPART  128

#define WS_MIN_BYTES ((size_t)2 * TOTAL * 4)            // 512 KiB min bits
#define PANEL_SLOTS  ((size_t)(TOTAL / 32) * 64)        // 131072 uint4 per side
#define PANELS_BYTES ((size_t)2 * PANEL_SLOTS * 16)     // 4 MiB both sides
#define WS_NEED      (WS_MIN_BYTES + PANELS_BYTES + (size_t)NPART * 4)

typedef __attribute__((ext_vector_type(8)))  short short8;
typedef __attribute__((ext_vector_type(16))) float f32x16;

__device__ __forceinline__ unsigned short f2bf(float x) {
    union { float f; unsigned u; } v; v.f = x;
    unsigned r = v.u + 0x7FFFu + ((v.u >> 16) & 1u);    // RNE
    return (unsigned short)(r >> 16);
}
__device__ __forceinline__ float bf2f(unsigned short h) {
    union { float f; unsigned u; } v; v.u = ((unsigned)h) << 16; return v.f;
}

// B-role slots, k = 8*g + j (A and B use the SAME k-map; sum is perm-invariant):
//  k0-2: -2bH(xyz)  k3-5: -2bL(xyz)  k6-8: -2bH(xyz)  k9,10: 1,1
//  k11,12: b2H,b2L  k13-15: 0
__device__ __forceinline__ uint4 make_bslots(const float* __restrict__ pts,
                                             int tile, int lane) {
    const int pidx = lane & 31, g = lane >> 5;
    const float* pp = pts + (size_t)(tile * 32 + pidx) * 3;
    const float x = pp[0], y = pp[1], z = pp[2];
    const unsigned short xh = f2bf(x), yh = f2bf(y), zh = f2bf(z);
    const unsigned short xl = f2bf(x - bf2f(xh)), yl = f2bf(y - bf2f(yh)),
                         zl = f2bf(z - bf2f(zh));
    const unsigned short m2xh = f2bf(-2.0f * bf2f(xh)), m2yh = f2bf(-2.0f * bf2f(yh)),
                         m2zh = f2bf(-2.0f * bf2f(zh));
    const unsigned short m2xl = f2bf(-2.0f * bf2f(xl)), m2yl = f2bf(-2.0f * bf2f(yl)),
                         m2zl = f2bf(-2.0f * bf2f(zl));
    const float s2 = fmaf(x, x, fmaf(y, y, z * z));
    const unsigned short s2h = f2bf(s2);
    const unsigned short s2l = f2bf(s2 - bf2f(s2h));
    const unsigned short ONE = 0x3F80;
    unsigned short s[8];
    if (g == 0) { s[0]=m2xh; s[1]=m2yh; s[2]=m2zh; s[3]=m2xl; s[4]=m2yl; s[5]=m2zl; s[6]=m2xh; s[7]=m2yh; }
    else        { s[0]=m2zh; s[1]=ONE;  s[2]=ONE;  s[3]=s2h;  s[4]=s2l;  s[5]=0;    s[6]=0;    s[7]=0;   }
    uint4 o;
    o.x = (unsigned)s[0] | ((unsigned)s[1] << 16);
    o.y = (unsigned)s[2] | ((unsigned)s[3] << 16);
    o.z = (unsigned)s[4] | ((unsigned)s[5] << 16);
    o.w = (unsigned)s[6] | ((unsigned)s[7] << 16);
    return o;
}

// A-role slots paired with B above: k0-2 aH, k3-5 aH, k6-8 aL, k9 a2H,
// k10 a2L, k11,12: 1,1, k13-15: 0.
__device__ __forceinline__ short8 make_aslots(const float* __restrict__ pts,
                                              int point, int g) {
    const float* pp = pts + (size_t)point * 3;
    const float x = pp[0], y = pp[1], z = pp[2];
    const unsigned short xh = f2bf(x), yh = f2bf(y), zh = f2bf(z);
    const unsigned short xl = f2bf(x - bf2f(xh)), yl = f2bf(y - bf2f(yh)),
                         zl = f2bf(z - bf2f(zh));
    const float s2 = fmaf(x, x, fmaf(y, y, z * z));
    const unsigned short s2h = f2bf(s2);
    const unsigned short s2l = f2bf(s2 - bf2f(s2h));
    const unsigned short ONE = 0x3F80;
    unsigned short s[8];
    if (g == 0) { s[0]=xh; s[1]=yh; s[2]=zh; s[3]=xh; s[4]=yh; s[5]=zh; s[6]=xl; s[7]=yl; }
    else        { s[0]=zl; s[1]=s2h; s[2]=s2l; s[3]=ONE; s[4]=ONE; s[5]=0; s[6]=0; s[7]=0; }
    union { unsigned u[4]; short8 v; } o;
    o.u[0] = (unsigned)s[0] | ((unsigned)s[1] << 16);
    o.u[1] = (unsigned)s[2] | ((unsigned)s[3] << 16);
    o.u[2] = (unsigned)s[4] | ((unsigned)s[5] << 16);
    o.u[3] = (unsigned)s[6] | ((unsigned)s[7] << 16);
    return o.v;
}

// Build both fragment panels AND init wsmin. panels side0=p1, side1=p2.
__global__ __launch_bounds__(256) void cd_prep(const float* __restrict__ p1,
                                               const float* __restrict__ p2,
                                               uint4* __restrict__ panels,
                                               unsigned* __restrict__ wsmin) {
    const int tid = blockIdx.x * 256 + threadIdx.x;   // [0, 262144)
    if (tid < 2 * TOTAL) wsmin[tid] = 0x7F800000u;    // +inf
    const int s2   = tid >> 17;                       // 131072 slots per side
    const int l    = tid & 131071;
    const float* pts = s2 ? p2 : p1;
    panels[((size_t)s2 << 17) + l] = make_bslots(pts, l >> 6, l & 63);
}

// Main: wave = 128 rows (4 row-subtiles), block = 4 waves = 512 rows.
// Each block sweeps 32 col-tiles; colgroups combined via atomicMin.
// grid = (16 batches * 8 rowgroups * 4 colgroups, 2 dirs) = (512, 2).
// 1024 blocks * 4 waves = 16 waves/CU = 4/SIMD  (the R6 fix: TLP).
__global__ __launch_bounds__(256) void cd_mfma(
        const float* __restrict__ p1, const float* __restrict__ p2,
        const uint4* __restrict__ panels, unsigned* __restrict__ wsmin) {
    const int dir  = blockIdx.y;
    const float* __restrict__ A = dir ? p2 : p1;
    const uint4* __restrict__ panel = panels + ((size_t)(dir ? 0 : 1) << 17);
    unsigned* __restrict__ outmin = wsmin + dir * TOTAL;

    const int bx   = blockIdx.x;
    const int b    = bx >> 5;                         // batch
    const int rg   = (bx >> 2) & 7;                   // rowgroup (512 rows)
    const int cg   = bx & 3;                          // colgroup (32 col-tiles)
    const int wave = threadIdx.x >> 6;
    const int lane = threadIdx.x & 63;
    const int pidx = lane & 31, g = lane >> 5;

    const int rowbase = b * NPTS + rg * 512 + wave * 128;

    const short8 a0 = make_aslots(A, rowbase       + pidx, g);
    const short8 a1 = make_aslots(A, rowbase + 32  + pidx, g);
    const short8 a2 = make_aslots(A, rowbase + 64  + pidx, g);
    const short8 a3 = make_aslots(A, rowbase + 96  + pidx, g);

    f32x16 zero, r0, r1, r2, r3;
#pragma unroll
    for (int e = 0; e < 16; ++e) {
        zero[e] = 0.0f; r0[e] = 3.0e38f; r1[e] = 3.0e38f;
        r2[e] = 3.0e38f; r3[e] = 3.0e38f;
    }

    const uint4* __restrict__ fp =
        panel + ((size_t)(b * 128 + cg * 32) * 64) + lane;

    auto compute = [&](uint4 fa, uint4 fb) {
        const short8 b0 = *reinterpret_cast<const short8*>(&fa);
        const short8 b1 = *reinterpret_cast<const short8*>(&fb);
        f32x16 d0, d1;
        d0 = __builtin_amdgcn_mfma_f32_32x32x16_bf16(a0, b0, zero, 0, 0, 0);
        d1 = __builtin_amdgcn_mfma_f32_32x32x16_bf16(a0, b1, zero, 0, 0, 0);
#pragma unroll
        for (int e = 0; e < 16; ++e) {
            float t; asm("v_min3_f32 %0, %1, %2, %3" : "=v"(t)
                         : "v"(r0[e]), "v"(d0[e]), "v"(d1[e])); r0[e] = t;
        }
        d0 = __builtin_amdgcn_mfma_f32_32x32x16_bf16(a1, b0, zero, 0, 0, 0);
        d1 = __builtin_amdgcn_mfma_f32_32x32x16_bf16(a1, b1, zero, 0, 0, 0);
#pragma unroll
        for (int e = 0; e < 16; ++e) {
            float t; asm("v_min3_f32 %0, %1, %2, %3" : "=v"(t)
                         : "v"(r1[e]), "v"(d0[e]), "v"(d1[e])); r1[e] = t;
        }
        d0 = __builtin_amdgcn_mfma_f32_32x32x16_bf16(a2, b0, zero, 0, 0, 0);
        d1 = __builtin_amdgcn_mfma_f32_32x32x16_bf16(a2, b1, zero, 0, 0, 0);
#pragma unroll
        for (int e = 0; e < 16; ++e) {
            float t; asm("v_min3_f32 %0, %1, %2, %3" : "=v"(t)
                         : "v"(r2[e]), "v"(d0[e]), "v"(d1[e])); r2[e] = t;
        }
        d0 = __builtin_amdgcn_mfma_f32_32x32x16_bf16(a3, b0, zero, 0, 0, 0);
        d1 = __builtin_amdgcn_mfma_f32_32x32x16_bf16(a3, b1, zero, 0, 0, 0);
#pragma unroll
        for (int e = 0; e < 16; ++e) {
            float t; asm("v_min3_f32 %0, %1, %2, %3" : "=v"(t)
                         : "v"(r3[e]), "v"(d0[e]), "v"(d1[e])); r3[e] = t;
        }
    };

    // Depth-1 pair pipeline; every tile computed exactly once (R6 tail fix).
    uint4 c0 = fp[0], c1 = fp[64];
#pragma unroll 1
    for (int t = 0; t < 32; t += 2) {
        const int tn = (t + 2 < 32) ? (t + 2) : 30;   // clamp affects PREFETCH only
        uint4 n0 = fp[(size_t)tn * 64];
        uint4 n1 = fp[(size_t)tn * 64 + 64];
        compute(c0, c1);
        c0 = n0; c1 = n1;
    }

    // Row-min across the 32 columns (butterfly within each 32-lane half),
    // then one atomicMin per row. Row-in-tile = (e&3)+8*(e>>2)+4g (m74/m101).
#pragma unroll
    for (int e = 0; e < 16; ++e) {
        float v0 = r0[e], v1 = r1[e], v2 = r2[e], v3 = r3[e];
#pragma unroll
        for (int m = 1; m <= 16; m <<= 1) {
            v0 = fminf(v0, __shfl_xor(v0, m));
            v1 = fminf(v1, __shfl_xor(v1, m));
            v2 = fminf(v2, __shfl_xor(v2, m));
            v3 = fminf(v3, __shfl_xor(v3, m));
        }
        const int rl = (e & 3) + 8 * (e >> 2) + 4 * g;
        if (pidx == 0) {
            atomicMin(&outmin[rowbase +      rl], __float_as_uint(fmaxf(v0, 0.0f)));
            atomicMin(&outmin[rowbase + 32 + rl], __float_as_uint(fmaxf(v1, 0.0f)));
            atomicMin(&outmin[rowbase + 64 + rl], __float_as_uint(fmaxf(v2, 0.0f)));
            atomicMin(&outmin[rowbase + 96 + rl], __float_as_uint(fmaxf(v3, 0.0f)));
        }
    }
}

// ---------------- deterministic two-stage sum ----------------
__global__ __launch_bounds__(256) void cd_reduce1(const float* __restrict__ wsmin,
                                                  float* __restrict__ partial) {
    __shared__ float sred[256];
    const float4* __restrict__ v = (const float4*)wsmin;
    const int i = blockIdx.x * 256 + threadIdx.x;     // 128*256 == 2*TOTAL/4
    float4 x = v[i];
    sred[threadIdx.x] = (x.x + x.y) + (x.z + x.w);
    __syncthreads();
    for (int st = 128; st > 0; st >>= 1) {
        if (threadIdx.x < st) sred[threadIdx.x] += sred[threadIdx.x + st];
        __syncthreads();
    }
    if (threadIdx.x == 0) partial[blockIdx.x] = sred[0];
}

__global__ __launch_bounds__(NPART) void cd_reduce2(const float* __restrict__ partial,
                                                    float* __restrict__ out) {
    __shared__ float sred[NPART];
    sred[threadIdx.x] = partial[threadIdx.x];
    __syncthreads();
    for (int st = NPART / 2; st > 0; st >>= 1) {
        if (threadIdx.x < st) sred[threadIdx.x] += sred[threadIdx.x + st];
        __syncthreads();
    }
    if (threadIdx.x == 0) out[0] = sred[0] * (1.0f / (float)BQ);
}

// ---------------- fallback (ws too small): R2 LDS-scalar path ----------------
__global__ __launch_bounds__(256) void cd_init_ws(unsigned int* __restrict__ ws) {
    ws[blockIdx.x * 256 + threadIdx.x] = 0x7F800000u;
}
#define F_APT 8
__global__ __launch_bounds__(256) void cd_min_lds(
        const float* __restrict__ p1, const float* __restrict__ p2,
        unsigned int* __restrict__ wsmin) {
    const int dir = blockIdx.y;
    const float* __restrict__ Aset = dir ? p2 : p1;
    const float* __restrict__ Bset = dir ? p1 : p2;
    unsigned int* __restrict__ outmin = wsmin + dir * TOTAL;
    const int atile = blockIdx.x / 16;
    const int mtile = blockIdx.x % 16;
    const int a0 = atile * 2048;
    const int m0 = (a0 / NPTS) * NPTS + mtile * 256;
    __shared__ float4 sbf[256];
    {
        const float* bp = Bset + (size_t)(m0 + threadIdx.x) * 3;
        float bx = bp[0], by = bp[1], bz = bp[2];
        sbf[threadIdx.x] = make_float4(-2.0f*bx, -2.0f*by, -2.0f*bz,
                                       fmaf(bx,bx,fmaf(by,by,bz*bz)));
    }
    __syncthreads();
    float ax[F_APT], ay[F_APT], az[F_APT], q2[F_APT], mn[F_APT];
#pragma unroll
    for (int k = 0; k < F_APT; ++k) {
        const int ai = a0 + k*256 + threadIdx.x;
        const float* ap = Aset + (size_t)ai * 3;
        ax[k]=ap[0]; ay[k]=ap[1]; az[k]=ap[2];
        q2[k]=fmaf(ax[k],ax[k],fmaf(ay[k],ay[k],az[k]*az[k]));
        mn[k]=3.0e38f;
    }
#pragma unroll 2
    for (int j = 0; j < 256; j += 2) {
        const float4 b0 = sbf[j], b1 = sbf[j+1];
#pragma unroll
        for (int k = 0; k < F_APT; ++k) {
            float d0 = fmaf(az[k],b0.z,b0.w); d0=fmaf(ay[k],b0.y,d0); d0=fmaf(ax[k],b0.x,d0);
            float d1 = fmaf(az[k],b1.z,b1.w); d1=fmaf(ay[k],b1.y,d1); d1=fmaf(ax[k],b1.x,d1);
            asm("v_min3_f32 %0, %1, %2, %3" : "=v"(mn[k]) : "v"(mn[k]), "v"(d0), "v"(d1));
        }
    }
#pragma unroll
    for (int k = 0; k < F_APT; ++k) {
        const int ai = a0 + k*256 + threadIdx.x;
        atomicMin(&outmin[ai], __float_as_uint(fmaxf(q2[k]+mn[k], 0.0f)));
    }
}
__global__ __launch_bounds__(1024) void cd_reduce_single(const float* __restrict__ wsmin,
                                                         float* __restrict__ out) {
    __shared__ float sred[1024];
    const float4* __restrict__ v = (const float4*)wsmin;
    float s = 0.0f;
    for (int i = threadIdx.x; i < (2*TOTAL)/4; i += 1024) {
        float4 x = v[i]; s += (x.x + x.y) + (x.z + x.w);
    }
    sred[threadIdx.x] = s;
    __syncthreads();
    for (int st = 512; st > 0; st >>= 1) {
        if (threadIdx.x < st) sred[threadIdx.x] += sred[threadIdx.x + st];
        __syncthreads();
    }
    if (threadIdx.x == 0) out[0] = sred[0] * (1.0f / (float)BQ);
}

extern "C" void kernel_launch(void* const* d_in, const int* in_sizes, int n_in,
                              void* d_out, int out_size, void* d_ws, size_t ws_size,
                              hipStream_t stream) {
    const float* p1 = (const float*)d_in[0];
    const float* p2 = (const float*)d_in[1];
    float* out = (float*)d_out;

    if (ws_size >= WS_NEED) {
        unsigned* wsmin = (unsigned*)d_ws;
        uint4* panels = (uint4*)((char*)d_ws + WS_MIN_BYTES);
        float* partial = (float*)((char*)d_ws + WS_MIN_BYTES + PANELS_BYTES);
        cd_prep<<<1024, 256, 0, stream>>>(p1, p2, panels, wsmin);
        dim3 grid(512, 2, 1);
        cd_mfma<<<grid, 256, 0, stream>>>(p1, p2, panels, wsmin);
        cd_reduce1<<<128, 256, 0, stream>>>((const float*)wsmin, partial);
        cd_reduce2<<<1, NPART, 0, stream>>>(partial, out);
    } else {
        unsigned* wsmin = (unsigned*)d_ws;                   // 512 KiB
        cd_init_ws<<<(2 * TOTAL) / 256, 256, 0, stream>>>(wsmin);
        dim3 grid(512, 2, 1);
        cd_min_lds<<<grid, 256, 0, stream>>>(p1, p2, wsmin);
        cd_reduce_single<<<1, 1024, 0, stream>>>((const float*)wsmin, out);
    }
}

// Round 8
// 52.297 us; speedup vs baseline: 1.1648x; 1.0378x over previous
//
#include <hip/hip_runtime.h>

// ChamferDistance  B=16, N=M=4096, D=3, fp32 in/out (scalar out).
// Single-pass MFMA: dist matrix computed ONCE per batch; row-mins -> p1 side,
// col-mins -> p2 side.  d(a,b) = sum_k A[k]*B[k], 13 bf16 hi/lo slots, K=16.
#define BQ     16
#define NPTS   4096
#define TOTAL  (BQ * NPTS)          // 65536 points per side
#define NPART  128

#define WS_MIN_BYTES  ((size_t)2 * TOTAL * 4)           // 512 KiB min values
#define PANEL_SLOTS   ((size_t)(TOTAL / 32) * 64)       // 131072 uint4 (p2 side)
#define PANEL_BYTES   (PANEL_SLOTS * 16)                // 2 MiB
#define COLPART_BYTES ((size_t)16 * TOTAL * 4)          // 4 MiB (16 rowgroups)
#define WS_NEED (WS_MIN_BYTES + PANEL_BYTES + COLPART_BYTES + (size_t)NPART * 4)

typedef __attribute__((ext_vector_type(8)))  short short8;
typedef __attribute__((ext_vector_type(16))) float f32x16;

__device__ __forceinline__ unsigned short f2bf(float x) {
    union { float f; unsigned u; } v; v.f = x;
    unsigned r = v.u + 0x7FFFu + ((v.u >> 16) & 1u);    // RNE
    return (unsigned short)(r >> 16);
}
__device__ __forceinline__ float bf2f(unsigned short h) {
    union { float f; unsigned u; } v; v.u = ((unsigned)h) << 16; return v.f;
}

// B-role slots, k = 8*g + j:
//  k0-2: -2bH(xyz)  k3-5: -2bL(xyz)  k6-8: -2bH(xyz)  k9,10: 1,1
//  k11,12: b2H,b2L  k13-15: 0
__device__ __forceinline__ uint4 make_bslots(const float* __restrict__ pts,
                                             int tile, int lane) {
    const int pidx = lane & 31, g = lane >> 5;
    const float* pp = pts + (size_t)(tile * 32 + pidx) * 3;
    const float x = pp[0], y = pp[1], z = pp[2];
    const unsigned short xh = f2bf(x), yh = f2bf(y), zh = f2bf(z);
    const unsigned short xl = f2bf(x - bf2f(xh)), yl = f2bf(y - bf2f(yh)),
                         zl = f2bf(z - bf2f(zh));
    const unsigned short m2xh = f2bf(-2.0f * bf2f(xh)), m2yh = f2bf(-2.0f * bf2f(yh)),
                         m2zh = f2bf(-2.0f * bf2f(zh));
    const unsigned short m2xl = f2bf(-2.0f * bf2f(xl)), m2yl = f2bf(-2.0f * bf2f(yl)),
                         m2zl = f2bf(-2.0f * bf2f(zl));
    const float s2 = fmaf(x, x, fmaf(y, y, z * z));
    const unsigned short s2h = f2bf(s2);
    const unsigned short s2l = f2bf(s2 - bf2f(s2h));
    const unsigned short ONE = 0x3F80;
    unsigned short s[8];
    if (g == 0) { s[0]=m2xh; s[1]=m2yh; s[2]=m2zh; s[3]=m2xl; s[4]=m2yl; s[5]=m2zl; s[6]=m2xh; s[7]=m2yh; }
    else        { s[0]=m2zh; s[1]=ONE;  s[2]=ONE;  s[3]=s2h;  s[4]=s2l;  s[5]=0;    s[6]=0;    s[7]=0;   }
    uint4 o;
    o.x = (unsigned)s[0] | ((unsigned)s[1] << 16);
    o.y = (unsigned)s[2] | ((unsigned)s[3] << 16);
    o.z = (unsigned)s[4] | ((unsigned)s[5] << 16);
    o.w = (unsigned)s[6] | ((unsigned)s[7] << 16);
    return o;
}

// A-role slots paired with B: k0-2 aH, k3-5 aH, k6-8 aL, k9 a2H, k10 a2L,
// k11,12: 1,1, k13-15: 0.
__device__ __forceinline__ short8 make_aslots(const float* __restrict__ pts,
                                              int point, int g) {
    const float* pp = pts + (size_t)point * 3;
    const float x = pp[0], y = pp[1], z = pp[2];
    const unsigned short xh = f2bf(x), yh = f2bf(y), zh = f2bf(z);
    const unsigned short xl = f2bf(x - bf2f(xh)), yl = f2bf(y - bf2f(yh)),
                         zl = f2bf(z - bf2f(zh));
    const float s2 = fmaf(x, x, fmaf(y, y, z * z));
    const unsigned short s2h = f2bf(s2);
    const unsigned short s2l = f2bf(s2 - bf2f(s2h));
    const unsigned short ONE = 0x3F80;
    unsigned short s[8];
    if (g == 0) { s[0]=xh; s[1]=yh; s[2]=zh; s[3]=xh; s[4]=yh; s[5]=zh; s[6]=xl; s[7]=yl; }
    else        { s[0]=zl; s[1]=s2h; s[2]=s2l; s[3]=ONE; s[4]=ONE; s[5]=0; s[6]=0; s[7]=0; }
    union { unsigned u[4]; short8 v; } o;
    o.u[0] = (unsigned)s[0] | ((unsigned)s[1] << 16);
    o.u[1] = (unsigned)s[2] | ((unsigned)s[3] << 16);
    o.u[2] = (unsigned)s[4] | ((unsigned)s[5] << 16);
    o.u[3] = (unsigned)s[6] | ((unsigned)s[7] << 16);
    return o.v;
}

// Build p2 fragment panel + init row-side wsmin to +inf.
__global__ __launch_bounds__(256) void cd_prep(const float* __restrict__ p2,
                                               uint4* __restrict__ panel,
                                               unsigned* __restrict__ wsmin) {
    const int tid = blockIdx.x * 256 + threadIdx.x;   // [0, 131072)
    if (tid < TOTAL) wsmin[tid] = 0x7F800000u;
    panel[tid] = make_bslots(p2, tid >> 6, tid & 63);
}

// Main: wave = 64 rows (2 subtiles) x 32 col-tiles. Block = 4 waves (256 rows).
// grid = 16 batches * 16 rowgroups * 4 colgroups = 1024 blocks.
// Row-mins: butterfly + atomicMin.  Col-mins: e-tree -> LDS -> colpart[rg].
__global__ __launch_bounds__(256) void cd_sym(
        const float* __restrict__ p1, const uint4* __restrict__ panel,
        unsigned* __restrict__ wsmin, unsigned* __restrict__ colpart) {
    const int bx   = blockIdx.x;
    const int b    = bx >> 6;                         // batch
    const int rg   = (bx >> 2) & 15;                  // rowgroup (256 rows)
    const int cg   = bx & 3;                          // colgroup (32 col-tiles)
    const int wave = threadIdx.x >> 6;
    const int lane = threadIdx.x & 63;
    const int pidx = lane & 31, g = lane >> 5;

    const int rowbase = b * NPTS + rg * 256 + wave * 64;

    const short8 a0 = make_aslots(p1, rowbase      + pidx, g);
    const short8 a1 = make_aslots(p1, rowbase + 32 + pidx, g);

    __shared__ unsigned colbuf[1024];                 // 32 tiles * 32 cols
    for (int i = threadIdx.x; i < 1024; i += 256) colbuf[i] = 0x7F800000u;
    __syncthreads();

    f32x16 zero, r0, r1;
#pragma unroll
    for (int e = 0; e < 16; ++e) { zero[e] = 0.0f; r0[e] = 3.0e38f; r1[e] = 3.0e38f; }

    const uint4* __restrict__ fp =
        panel + ((size_t)(b * 128 + cg * 32) * 64) + lane;

    uint4 c0 = fp[0], c1 = fp[64];
#pragma unroll 1
    for (int t = 0; t < 32; t += 2) {
        const int tn = (t + 2 < 32) ? (t + 2) : 30;   // clamp affects prefetch only
        uint4 n0 = fp[(size_t)tn * 64];
        uint4 n1 = fp[(size_t)tn * 64 + 64];

        const short8 b0 = *reinterpret_cast<const short8*>(&c0);
        const short8 b1 = *reinterpret_cast<const short8*>(&c1);
        f32x16 d00 = __builtin_amdgcn_mfma_f32_32x32x16_bf16(a0, b0, zero, 0, 0, 0);
        f32x16 d01 = __builtin_amdgcn_mfma_f32_32x32x16_bf16(a0, b1, zero, 0, 0, 0);
        f32x16 d10 = __builtin_amdgcn_mfma_f32_32x32x16_bf16(a1, b0, zero, 0, 0, 0);
        f32x16 d11 = __builtin_amdgcn_mfma_f32_32x32x16_bf16(a1, b1, zero, 0, 0, 0);

        // row-mins (each element once; fminf nests -> v_min3 fusion)
#pragma unroll
        for (int e = 0; e < 16; ++e) {
            r0[e] = fminf(r0[e], fminf(d00[e], d01[e]));
            r1[e] = fminf(r1[e], fminf(d10[e], d11[e]));
        }

        // col-min for tile t (cols = lane&31): tree over the wave's 32 rows
        {
            float m = fminf(d00[0], d10[0]);
#pragma unroll
            for (int e = 1; e < 15; e += 2)
                m = fminf(fminf(m, fminf(d00[e], d10[e])),
                          fminf(d00[e + 1], d10[e + 1]));
            m = fminf(m, fminf(d00[15], d10[15]));
            m = fminf(m, __shfl_xor(m, 32));
            if (g == 0)
                atomicMin(&colbuf[t * 32 + pidx], __float_as_uint(fmaxf(m, 0.0f)));
        }
        // col-min for tile t+1
        {
            float m = fminf(d01[0], d11[0]);
#pragma unroll
            for (int e = 1; e < 15; e += 2)
                m = fminf(fminf(m, fminf(d01[e], d11[e])),
                          fminf(d01[e + 1], d11[e + 1]));
            m = fminf(m, fminf(d01[15], d11[15]));
            m = fminf(m, __shfl_xor(m, 32));
            if (g == 0)
                atomicMin(&colbuf[(t + 1) * 32 + pidx], __float_as_uint(fmaxf(m, 0.0f)));
        }
        c0 = n0; c1 = n1;
    }

    // Row epilogue: butterfly min over 32 cols, atomicMin per row.
    // Row-in-tile = (e&3)+8*(e>>2)+4g  (m74/m101 layout).
#pragma unroll
    for (int e = 0; e < 16; ++e) {
        float v0 = r0[e], v1 = r1[e];
#pragma unroll
        for (int m = 1; m <= 16; m <<= 1) {
            v0 = fminf(v0, __shfl_xor(v0, m));
            v1 = fminf(v1, __shfl_xor(v1, m));
        }
        const int rl = (e & 3) + 8 * (e >> 2) + 4 * g;
        if (pidx == 0) {
            atomicMin(&wsmin[rowbase +      rl], __float_as_uint(fmaxf(v0, 0.0f)));
            atomicMin(&wsmin[rowbase + 32 + rl], __float_as_uint(fmaxf(v1, 0.0f)));
        }
    }

    // Col writeout: block's 1024 cols -> colpart[rg][global col] (no atomics).
    __syncthreads();
    const size_t cbase = (size_t)rg * TOTAL + (size_t)b * NPTS + (size_t)cg * 1024;
    for (int i = threadIdx.x; i < 1024; i += 256)
        colpart[cbase + i] = colbuf[i];
}

// Combine 16 rowgroup col-partials -> col-side wsmin.
__global__ __launch_bounds__(256) void cd_colmin(const unsigned* __restrict__ colpart,
                                                 unsigned* __restrict__ wsmin) {
    const int c = blockIdx.x * 256 + threadIdx.x;     // [0, TOTAL)
    unsigned m = colpart[c];
#pragma unroll
    for (int rgi = 1; rgi < 16; ++rgi)
        m = min(m, colpart[(size_t)rgi * TOTAL + c]);
    wsmin[TOTAL + c] = m;                             // uint order == float order (>=0)
}

// ---------------- deterministic two-stage sum ----------------
__global__ __launch_bounds__(256) void cd_reduce1(const float* __restrict__ wsmin,
                                                  float* __restrict__ partial) {
    __shared__ float sred[256];
    const float4* __restrict__ v = (const float4*)wsmin;
    const int i = blockIdx.x * 256 + threadIdx.x;     // 128*256 == 2*TOTAL/4
    float4 x = v[i];
    sred[threadIdx.x] = (x.x + x.y) + (x.z + x.w);
    __syncthreads();
    for (int st = 128; st > 0; st >>= 1) {
        if (threadIdx.x < st) sred[threadIdx.x] += sred[threadIdx.x + st];
        __syncthreads();
    }
    if (threadIdx.x == 0) partial[blockIdx.x] = sred[0];
}

__global__ __launch_bounds__(NPART) void cd_reduce2(const float* __restrict__ partial,
                                                    float* __restrict__ out) {
    __shared__ float sred[NPART];
    sred[threadIdx.x] = partial[threadIdx.x];
    __syncthreads();
    for (int st = NPART / 2; st > 0; st >>= 1) {
        if (threadIdx.x < st) sred[threadIdx.x] += sred[threadIdx.x + st];
        __syncthreads();
    }
    if (threadIdx.x == 0) out[0] = sred[0] * (1.0f / (float)BQ);
}

// ---------------- fallback (ws too small): R2 LDS-scalar path ----------------
__global__ __launch_bounds__(256) void cd_init_ws(unsigned int* __restrict__ ws) {
    ws[blockIdx.x * 256 + threadIdx.x] = 0x7F800000u;
}
#define F_APT 8
__global__ __launch_bounds__(256) void cd_min_lds(
        const float* __restrict__ p1, const float* __restrict__ p2,
        unsigned int* __restrict__ wsmin) {
    const int dir = blockIdx.y;
    const float* __restrict__ Aset = dir ? p2 : p1;
    const float* __restrict__ Bset = dir ? p1 : p2;
    unsigned int* __restrict__ outmin = wsmin + dir * TOTAL;
    const int atile = blockIdx.x / 16;
    const int mtile = blockIdx.x % 16;
    const int a0 = atile * 2048;
    const int m0 = (a0 / NPTS) * NPTS + mtile * 256;
    __shared__ float4 sbf[256];
    {
        const float* bp = Bset + (size_t)(m0 + threadIdx.x) * 3;
        float bx = bp[0], by = bp[1], bz = bp[2];
        sbf[threadIdx.x] = make_float4(-2.0f*bx, -2.0f*by, -2.0f*bz,
                                       fmaf(bx,bx,fmaf(by,by,bz*bz)));
    }
    __syncthreads();
    float ax[F_APT], ay[F_APT], az[F_APT], q2[F_APT], mn[F_APT];
#pragma unroll
    for (int k = 0; k < F_APT; ++k) {
        const int ai = a0 + k*256 + threadIdx.x;
        const float* ap = Aset + (size_t)ai * 3;
        ax[k]=ap[0]; ay[k]=ap[1]; az[k]=ap[2];
        q2[k]=fmaf(ax[k],ax[k],fmaf(ay[k],ay[k],az[k]*az[k]));
        mn[k]=3.0e38f;
    }
#pragma unroll 2
    for (int j = 0; j < 256; j += 2) {
        const float4 b0 = sbf[j], b1 = sbf[j+1];
#pragma unroll
        for (int k = 0; k < F_APT; ++k) {
            float d0 = fmaf(az[k],b0.z,b0.w); d0=fmaf(ay[k],b0.y,d0); d0=fmaf(ax[k],b0.x,d0);
            float d1 = fmaf(az[k],b1.z,b1.w); d1=fmaf(ay[k],b1.y,d1); d1=fmaf(ax[k],b1.x,d1);
            mn[k] = fminf(fminf(mn[k], d0), d1);
        }
    }
#pragma unroll
    for (int k = 0; k < F_APT; ++k) {
        const int ai = a0 + k*256 + threadIdx.x;
        atomicMin(&outmin[ai], __float_as_uint(fmaxf(q2[k]+mn[k], 0.0f)));
    }
}
__global__ __launch_bounds__(1024) void cd_reduce_single(const float* __restrict__ wsmin,
                                                         float* __restrict__ out) {
    __shared__ float sred[1024];
    const float4* __restrict__ v = (const float4*)wsmin;
    float s = 0.0f;
    for (int i = threadIdx.x; i < (2*TOTAL)/4; i += 1024) {
        float4 x = v[i]; s += (x.x + x.y) + (x.z + x.w);
    }
    sred[threadIdx.x] = s;
    __syncthreads();
    for (int st = 512; st > 0; st >>= 1) {
        if (threadIdx.x < st) sred[threadIdx.x] += sred[threadIdx.x + st];
        __syncthreads();
    }
    if (threadIdx.x == 0) out[0] = sred[0] * (1.0f / (float)BQ);
}

extern "C" void kernel_launch(void* const* d_in, const int* in_sizes, int n_in,
                              void* d_out, int out_size, void* d_ws, size_t ws_size,
                              hipStream_t stream) {
    const float* p1 = (const float*)d_in[0];
    const float* p2 = (const float*)d_in[1];
    float* out = (float*)d_out;

    if (ws_size >= WS_NEED) {
        unsigned* wsmin = (unsigned*)d_ws;
        uint4* panel = (uint4*)((char*)d_ws + WS_MIN_BYTES);
        unsigned* colpart = (unsigned*)((char*)d_ws + WS_MIN_BYTES + PANEL_BYTES);
        float* partial = (float*)((char*)d_ws + WS_MIN_BYTES + PANEL_BYTES + COLPART_BYTES);

        cd_prep<<<512, 256, 0, stream>>>(p2, panel, wsmin);
        cd_sym<<<1024, 256, 0, stream>>>(p1, panel, wsmin, colpart);
        cd_colmin<<<TOTAL / 256, 256, 0, stream>>>(colpart, wsmin);
        cd_reduce1<<<128, 256, 0, stream>>>((const float*)wsmin, partial);
        cd_reduce2<<<1, NPART, 0, stream>>>(partial, out);
    } else {
        unsigned* wsmin = (unsigned*)d_ws;                   // 512 KiB
        cd_init_ws<<<(2 * TOTAL) / 256, 256, 0, stream>>>(wsmin);
        dim3 grid(512, 2, 1);
        cd_min_lds<<<grid, 256, 0, stream>>>(p1, p2, wsmin);
        cd_reduce_single<<<1, 1024, 0, stream>>>((const float*)wsmin, out);
    }
}

// Round 9
// 43.815 us; speedup vs baseline: 1.3902x; 1.1936x over previous
//
#include <hip/hip_runtime.h>

// ChamferDistance  B=16, N=M=4096, D=3, fp32 in/out (scalar out).
// Two cheap MFMA passes (dir0: rows of dist(p1,p2); dir1: rows of dist(p2,p1)).
// d(a,b) = sum_k A[k]*B[k], 13 bf16 hi/lo slots packed into K=32 (groups 0,1;
// groups 2,3 zero).  16x16x32 MFMA -> f32x4 accum, all state in VGPRs.
#define BQ     16
#define NPTS   4096
#define TOTAL  (BQ * NPTS)              // 65536 points per side
#define NPART  128
#define SIDE_TILES    (TOTAL / 16)      // 4096 col-tiles per side
#define PANEL_U4_SIDE ((size_t)SIDE_TILES * 32)   // 131072 uint4 per side (2 MiB)
#define ZERO_BYTES    4096
#define WS_MIN_BYTES  ((size_t)2 * TOTAL * 4)     // 512 KiB
#define WS_NEED (WS_MIN_BYTES + ZERO_BYTES + 2 * PANEL_U4_SIDE * 16 + (size_t)NPART * 4)

typedef __attribute__((ext_vector_type(8))) short short8;
typedef __attribute__((ext_vector_type(4))) float f32x4;

__device__ __forceinline__ unsigned short f2bf(float x) {
    union { float f; unsigned u; } v; v.f = x;
    unsigned r = v.u + 0x7FFFu + ((v.u >> 16) & 1u);    // RNE
    return (unsigned short)(r >> 16);
}
__device__ __forceinline__ float bf2f(unsigned short h) {
    union { float f; unsigned u; } v; v.u = ((unsigned)h) << 16; return v.f;
}
#define BF_ONE 0x3F80

// B-role, k-position (g, j), g = lane32>>4:
//  g0: m2xh m2yh m2zh m2xl m2yl m2zl m2xh m2yh
//  g1: m2zh  1    1   b2H  b2L   0    0    0
__device__ __forceinline__ uint4 make_bslots16(const float* __restrict__ pts,
                                               int tile, int lane32) {
    const int g = lane32 >> 4;
    const float* pp = pts + (size_t)(tile * 16 + (lane32 & 15)) * 3;
    const float x = pp[0], y = pp[1], z = pp[2];
    const unsigned short xh = f2bf(x), yh = f2bf(y), zh = f2bf(z);
    const unsigned short xl = f2bf(x - bf2f(xh)), yl = f2bf(y - bf2f(yh)),
                         zl = f2bf(z - bf2f(zh));
    const unsigned short m2xh = f2bf(-2.0f * bf2f(xh)), m2yh = f2bf(-2.0f * bf2f(yh)),
                         m2zh = f2bf(-2.0f * bf2f(zh));
    const unsigned short m2xl = f2bf(-2.0f * bf2f(xl)), m2yl = f2bf(-2.0f * bf2f(yl)),
                         m2zl = f2bf(-2.0f * bf2f(zl));
    const float s2 = fmaf(x, x, fmaf(y, y, z * z));
    const unsigned short s2h = f2bf(s2);
    const unsigned short s2l = f2bf(s2 - bf2f(s2h));
    unsigned short s[8];
    if (g == 0) { s[0]=m2xh; s[1]=m2yh; s[2]=m2zh; s[3]=m2xl;   s[4]=m2yl;   s[5]=m2zl; s[6]=m2xh; s[7]=m2yh; }
    else        { s[0]=m2zh; s[1]=BF_ONE; s[2]=BF_ONE; s[3]=s2h; s[4]=s2l;   s[5]=0;    s[6]=0;    s[7]=0;    }
    uint4 o;
    o.x = (unsigned)s[0] | ((unsigned)s[1] << 16);
    o.y = (unsigned)s[2] | ((unsigned)s[3] << 16);
    o.z = (unsigned)s[4] | ((unsigned)s[5] << 16);
    o.w = (unsigned)s[6] | ((unsigned)s[7] << 16);
    return o;
}

// A-role paired with B above:
//  g0: xh yh zh xh yh zh xl yl
//  g1: zl s2h s2l 1 1 0 0 0
__device__ __forceinline__ short8 make_aslots16(const float* __restrict__ pts,
                                                int point, int g) {
    const float* pp = pts + (size_t)point * 3;
    const float x = pp[0], y = pp[1], z = pp[2];
    const unsigned short xh = f2bf(x), yh = f2bf(y), zh = f2bf(z);
    const unsigned short xl = f2bf(x - bf2f(xh)), yl = f2bf(y - bf2f(yh)),
                         zl = f2bf(z - bf2f(zh));
    const float s2 = fmaf(x, x, fmaf(y, y, z * z));
    const unsigned short s2h = f2bf(s2);
    const unsigned short s2l = f2bf(s2 - bf2f(s2h));
    unsigned short s[8];
    if (g == 0) { s[0]=xh; s[1]=yh; s[2]=zh; s[3]=xh;     s[4]=yh;     s[5]=zh; s[6]=xl; s[7]=yl; }
    else        { s[0]=zl; s[1]=s2h; s[2]=s2l; s[3]=BF_ONE; s[4]=BF_ONE; s[5]=0; s[6]=0; s[7]=0; }
    union { unsigned u[4]; short8 v; } o;
    o.u[0] = (unsigned)s[0] | ((unsigned)s[1] << 16);
    o.u[1] = (unsigned)s[2] | ((unsigned)s[3] << 16);
    o.u[2] = (unsigned)s[4] | ((unsigned)s[5] << 16);
    o.u[3] = (unsigned)s[6] | ((unsigned)s[7] << 16);
    return o.v;
}

// Build both panels (side0 = p1, side1 = p2), init wsmin, zero the zero-block.
__global__ __launch_bounds__(256) void cd_prep(const float* __restrict__ p1,
                                               const float* __restrict__ p2,
                                               unsigned* __restrict__ wsmin,
                                               uint4* __restrict__ zerobuf,
                                               uint4* __restrict__ panels) {
    const int tid = blockIdx.x * 256 + threadIdx.x;   // [0, 262144)
    if (tid < 2 * TOTAL) wsmin[tid] = 0x7F800000u;    // +inf
    if (tid < 256) zerobuf[tid] = make_uint4(0, 0, 0, 0);
    const int side = tid >> 17;                       // 131072 slots per side
    const int l    = tid & 131071;
    const float* pts = side ? p2 : p1;
    panels[tid] = make_bslots16(pts, l >> 5, l & 31);
}

// Main: wave = 128 rows (8 x 16-row subtiles), block = 4 waves = 512 rows.
// Each wave sweeps 64 col-tiles (colgroup).  grid = (16b*8rg*4cg, 2 dirs).
// 1024 blocks * 4 waves = 16 waves/CU.  Row-mins elementwise (4-reg accums),
// one butterfly + 32 atomicMin per wave at the end.  No col trees, no asm.
__global__ __launch_bounds__(256, 4) void cd_pass(
        const float* __restrict__ p1, const float* __restrict__ p2,
        const uint4* __restrict__ zerobuf, const uint4* __restrict__ panels,
        unsigned* __restrict__ wsmin) {
    const int dir  = blockIdx.y;
    const float* __restrict__ A = dir ? p2 : p1;
    const uint4* __restrict__ panel = panels + (dir ? 0 : PANEL_U4_SIDE);
    unsigned* __restrict__ outmin = wsmin + dir * TOTAL;

    const int bx   = blockIdx.x;
    const int b    = bx >> 5;                         // batch
    const int rg   = (bx >> 2) & 7;                   // rowgroup (512 rows)
    const int cg   = bx & 3;                          // colgroup (64 col-tiles)
    const int wave = threadIdx.x >> 6;
    const int lane = threadIdx.x & 63;
    const int half = lane >> 5;                       // 0: real k-groups, 1: zeros

    const int rowbase = b * NPTS + rg * 512 + wave * 128;

    // A fragments: 8 subtiles of 16 rows; lanes >=32 carry zero k-groups.
    short8 az; { union { unsigned u[4]; short8 v; } z = {{0,0,0,0}}; az = z.v; }
    short8 a0=az,a1=az,a2=az,a3=az,a4=az,a5=az,a6=az,a7=az;
    if (half == 0) {
        const int g = (lane >> 4) & 1, r = lane & 15;
        a0 = make_aslots16(A, rowbase +   0 + r, g);
        a1 = make_aslots16(A, rowbase +  16 + r, g);
        a2 = make_aslots16(A, rowbase +  32 + r, g);
        a3 = make_aslots16(A, rowbase +  48 + r, g);
        a4 = make_aslots16(A, rowbase +  64 + r, g);
        a5 = make_aslots16(A, rowbase +  80 + r, g);
        a6 = make_aslots16(A, rowbase +  96 + r, g);
        a7 = make_aslots16(A, rowbase + 112 + r, g);
    }

    f32x4 zero = {0.0f, 0.0f, 0.0f, 0.0f};
    f32x4 r0,r1,r2,r3,r4,r5,r6,r7;
#pragma unroll
    for (int e = 0; e < 4; ++e) {
        r0[e]=3.0e38f; r1[e]=3.0e38f; r2[e]=3.0e38f; r3[e]=3.0e38f;
        r4[e]=3.0e38f; r5[e]=3.0e38f; r6[e]=3.0e38f; r7[e]=3.0e38f;
    }

    // Per-lane panel pointer: lanes>=32 point at the zero block, stride 0.
    const int tb = b * 256 + cg * 64;                 // first col-tile
    const uint4* base = (half == 0) ? (panel + (size_t)tb * 32 + lane)
                                    : (zerobuf + (lane & 31));
    const size_t stride = (half == 0) ? 32 : 0;       // uint4 per tile

#define CD_COMPUTE(C0, C1)                                                   \
    do {                                                                     \
        const short8 bf0 = *reinterpret_cast<const short8*>(&(C0));          \
        const short8 bf1 = *reinterpret_cast<const short8*>(&(C1));          \
        f32x4 d0, d1;                                                        \
        d0 = __builtin_amdgcn_mfma_f32_16x16x32_bf16(a0, bf0, zero, 0,0,0);  \
        d1 = __builtin_amdgcn_mfma_f32_16x16x32_bf16(a0, bf1, zero, 0,0,0);  \
        _Pragma("unroll") for (int e = 0; e < 4; ++e)                        \
            r0[e] = fminf(r0[e], fminf(d0[e], d1[e]));                       \
        d0 = __builtin_amdgcn_mfma_f32_16x16x32_bf16(a1, bf0, zero, 0,0,0);  \
        d1 = __builtin_amdgcn_mfma_f32_16x16x32_bf16(a1, bf1, zero, 0,0,0);  \
        _Pragma("unroll") for (int e = 0; e < 4; ++e)                        \
            r1[e] = fminf(r1[e], fminf(d0[e], d1[e]));                       \
        d0 = __builtin_amdgcn_mfma_f32_16x16x32_bf16(a2, bf0, zero, 0,0,0);  \
        d1 = __builtin_amdgcn_mfma_f32_16x16x32_bf16(a2, bf1, zero, 0,0,0);  \
        _Pragma("unroll") for (int e = 0; e < 4; ++e)                        \
            r2[e] = fminf(r2[e], fminf(d0[e], d1[e]));                       \
        d0 = __builtin_amdgcn_mfma_f32_16x16x32_bf16(a3, bf0, zero, 0,0,0);  \
        d1 = __builtin_amdgcn_mfma_f32_16x16x32_bf16(a3, bf1, zero, 0,0,0);  \
        _Pragma("unroll") for (int e = 0; e < 4; ++e)                        \
            r3[e] = fminf(r3[e], fminf(d0[e], d1[e]));                       \
        d0 = __builtin_amdgcn_mfma_f32_16x16x32_bf16(a4, bf0, zero, 0,0,0);  \
        d1 = __builtin_amdgcn_mfma_f32_16x16x32_bf16(a4, bf1, zero, 0,0,0);  \
        _Pragma("unroll") for (int e = 0; e < 4; ++e)                        \
            r4[e] = fminf(r4[e], fminf(d0[e], d1[e]));                       \
        d0 = __builtin_amdgcn_mfma_f32_16x16x32_bf16(a5, bf0, zero, 0,0,0);  \
        d1 = __builtin_amdgcn_mfma_f32_16x16x32_bf16(a5, bf1, zero, 0,0,0);  \
        _Pragma("unroll") for (int e = 0; e < 4; ++e)                        \
            r5[e] = fminf(r5[e], fminf(d0[e], d1[e]));                       \
        d0 = __builtin_amdgcn_mfma_f32_16x16x32_bf16(a6, bf0, zero, 0,0,0);  \
        d1 = __builtin_amdgcn_mfma_f32_16x16x32_bf16(a6, bf1, zero, 0,0,0);  \
        _Pragma("unroll") for (int e = 0; e < 4; ++e)                        \
            r6[e] = fminf(r6[e], fminf(d0[e], d1[e]));                       \
        d0 = __builtin_amdgcn_mfma_f32_16x16x32_bf16(a7, bf0, zero, 0,0,0);  \
        d1 = __builtin_amdgcn_mfma_f32_16x16x32_bf16(a7, bf1, zero, 0,0,0);  \
        _Pragma("unroll") for (int e = 0; e < 4; ++e)                        \
            r7[e] = fminf(r7[e], fminf(d0[e], d1[e]));                       \
    } while (0)

    // 64 tiles, 2 per iter, depth-1 register prefetch; exact coverage.
    uint4 c0 = base[0], c1 = base[stride];
    size_t off = 2 * stride;
#pragma unroll 1
    for (int i = 0; i < 31; ++i) {
        uint4 n0 = base[off], n1 = base[off + stride];
        off += 2 * stride;
        CD_COMPUTE(c0, c1);
        c0 = n0; c1 = n1;
    }
    CD_COMPUTE(c0, c1);
#undef CD_COMPUTE

    // Row epilogue: butterfly over the 16 cols (lanes 0-15 of each group),
    // then atomicMin per row.  Row = s*16 + (lane>>4)*4 + e  (m89/m91 layout).
    const int rgrp = lane >> 4;
#pragma unroll
    for (int s = 0; s < 8; ++s) {
        f32x4 rv = (s==0)?r0:(s==1)?r1:(s==2)?r2:(s==3)?r3:(s==4)?r4:(s==5)?r5:(s==6)?r6:r7;
#pragma unroll
        for (int e = 0; e < 4; ++e) {
            float v = rv[e];
            v = fminf(v, __shfl_xor(v, 1));
            v = fminf(v, __shfl_xor(v, 2));
            v = fminf(v, __shfl_xor(v, 4));
            v = fminf(v, __shfl_xor(v, 8));
            if ((lane & 15) == 0)
                atomicMin(&outmin[rowbase + s * 16 + rgrp * 4 + e],
                          __float_as_uint(fmaxf(v, 0.0f)));
        }
    }
}

// ---------------- deterministic two-stage sum ----------------
__global__ __launch_bounds__(256) void cd_reduce1(const float* __restrict__ wsmin,
                                                  float* __restrict__ partial) {
    __shared__ float sred[256];
    const float4* __restrict__ v = (const float4*)wsmin;
    const int i = blockIdx.x * 256 + threadIdx.x;     // 128*256 == 2*TOTAL/4
    float4 x = v[i];
    sred[threadIdx.x] = (x.x + x.y) + (x.z + x.w);
    __syncthreads();
    for (int st = 128; st > 0; st >>= 1) {
        if (threadIdx.x < st) sred[threadIdx.x] += sred[threadIdx.x + st];
        __syncthreads();
    }
    if (threadIdx.x == 0) partial[blockIdx.x] = sred[0];
}

__global__ __launch_bounds__(NPART) void cd_reduce2(const float* __restrict__ partial,
                                                    float* __restrict__ out) {
    __shared__ float sred[NPART];
    sred[threadIdx.x] = partial[threadIdx.x];
    __syncthreads();
    for (int st = NPART / 2; st > 0; st >>= 1) {
        if (threadIdx.x < st) sred[threadIdx.x] += sred[threadIdx.x + st];
        __syncthreads();
    }
    if (threadIdx.x == 0) out[0] = sred[0] * (1.0f / (float)BQ);
}

// ---------------- fallback (ws too small): R2 LDS-scalar path ----------------
__global__ __launch_bounds__(256) void cd_init_ws(unsigned int* __restrict__ ws) {
    ws[blockIdx.x * 256 + threadIdx.x] = 0x7F800000u;
}
#define F_APT 8
__global__ __launch_bounds__(256) void cd_min_lds(
        const float* __restrict__ p1, const float* __restrict__ p2,
        unsigned int* __restrict__ wsmin) {
    const int dir = blockIdx.y;
    const float* __restrict__ Aset = dir ? p2 : p1;
    const float* __restrict__ Bset = dir ? p1 : p2;
    unsigned int* __restrict__ outmin = wsmin + dir * TOTAL;
    const int atile = blockIdx.x / 16;
    const int mtile = blockIdx.x % 16;
    const int a0 = atile * 2048;
    const int m0 = (a0 / NPTS) * NPTS + mtile * 256;
    __shared__ float4 sbf[256];
    {
        const float* bp = Bset + (size_t)(m0 + threadIdx.x) * 3;
        float bx = bp[0], by = bp[1], bz = bp[2];
        sbf[threadIdx.x] = make_float4(-2.0f*bx, -2.0f*by, -2.0f*bz,
                                       fmaf(bx,bx,fmaf(by,by,bz*bz)));
    }
    __syncthreads();
    float ax[F_APT], ay[F_APT], az_[F_APT], q2[F_APT], mn[F_APT];
#pragma unroll
    for (int k = 0; k < F_APT; ++k) {
        const int ai = a0 + k*256 + threadIdx.x;
        const float* ap = Aset + (size_t)ai * 3;
        ax[k]=ap[0]; ay[k]=ap[1]; az_[k]=ap[2];
        q2[k]=fmaf(ax[k],ax[k],fmaf(ay[k],ay[k],az_[k]*az_[k]));
        mn[k]=3.0e38f;
    }
#pragma unroll 2
    for (int j = 0; j < 256; j += 2) {
        const float4 b0 = sbf[j], b1 = sbf[j+1];
#pragma unroll
        for (int k = 0; k < F_APT; ++k) {
            float d0 = fmaf(az_[k],b0.z,b0.w); d0=fmaf(ay[k],b0.y,d0); d0=fmaf(ax[k],b0.x,d0);
            float d1 = fmaf(az_[k],b1.z,b1.w); d1=fmaf(ay[k],b1.y,d1); d1=fmaf(ax[k],b1.x,d1);
            mn[k] = fminf(fminf(mn[k], d0), d1);
        }
    }
#pragma unroll
    for (int k = 0; k < F_APT; ++k) {
        const int ai = a0 + k*256 + threadIdx.x;
        atomicMin(&outmin[ai], __float_as_uint(fmaxf(q2[k]+mn[k], 0.0f)));
    }
}
__global__ __launch_bounds__(1024) void cd_reduce_single(const float* __restrict__ wsmin,
                                                         float* __restrict__ out) {
    __shared__ float sred[1024];
    const float4* __restrict__ v = (const float4*)wsmin;
    float s = 0.0f;
    for (int i = threadIdx.x; i < (2*TOTAL)/4; i += 1024) {
        float4 x = v[i]; s += (x.x + x.y) + (x.z + x.w);
    }
    sred[threadIdx.x] = s;
    __syncthreads();
    for (int st = 512; st > 0; st >>= 1) {
        if (threadIdx.x < st) sred[threadIdx.x] += sred[threadIdx.x + st];
        __syncthreads();
    }
    if (threadIdx.x == 0) out[0] = sred[0] * (1.0f / (float)BQ);
}

extern "C" void kernel_launch(void* const* d_in, const int* in_sizes, int n_in,
                              void* d_out, int out_size, void* d_ws, size_t ws_size,
                              hipStream_t stream) {
    const float* p1 = (const float*)d_in[0];
    const float* p2 = (const float*)d_in[1];
    float* out = (float*)d_out;

    if (ws_size >= WS_NEED) {
        unsigned* wsmin = (unsigned*)d_ws;
        uint4* zerobuf = (uint4*)((char*)d_ws + WS_MIN_BYTES);
        uint4* panels  = (uint4*)((char*)d_ws + WS_MIN_BYTES + ZERO_BYTES);
        float* partial = (float*)((char*)d_ws + WS_MIN_BYTES + ZERO_BYTES
                                  + 2 * PANEL_U4_SIDE * 16);

        cd_prep<<<1024, 256, 0, stream>>>(p1, p2, wsmin, zerobuf, panels);
        dim3 grid(512, 2, 1);
        cd_pass<<<grid, 256, 0, stream>>>(p1, p2, zerobuf, panels, wsmin);
        cd_reduce1<<<128, 256, 0, stream>>>((const float*)wsmin, partial);
        cd_reduce2<<<1, NPART, 0, stream>>>(partial, out);
    } else {
        unsigned* wsmin = (unsigned*)d_ws;                   // 512 KiB
        cd_init_ws<<<(2 * TOTAL) / 256, 256, 0, stream>>>(wsmin);
        dim3 grid(512, 2, 1);
        cd_min_lds<<<grid, 256, 0, stream>>>(p1, p2, wsmin);
        cd_reduce_single<<<1, 1024, 0, stream>>>((const float*)wsmin, out);
    }
}